// Round 6
// baseline (6172.105 us; speedup 1.0000x reference)
//
#include <hip/hip_runtime.h>
#include <hip/hip_fp16.h>

#define Bb 32
#define Ll 512
#define Dd 1024
#define Hh 256
#define Ee 64

__device__ __forceinline__ float sigmoidf_(float x) { return 1.f / (1.f + __expf(-x)); }
__device__ __forceinline__ float tanhf_(float x) { return 1.f - 2.f / (__expf(2.f * x) + 1.f); }

typedef _Float16 f16x2 __attribute__((ext_vector_type(2)));
typedef _Float16 v8hf __attribute__((ext_vector_type(8)));
typedef float v4f __attribute__((ext_vector_type(4)));
union Pk16 { uint4 u; f16x2 h2[4]; __half2 hh[4]; };

__device__ __forceinline__ float dot8(uint4 wv, uint4 hv, float acc) {
  Pk16 W, H;
  W.u = wv; H.u = hv;
#if __has_builtin(__builtin_amdgcn_fdot2)
#pragma unroll
  for (int i = 0; i < 4; i++)
    acc = __builtin_amdgcn_fdot2(W.h2[i], H.h2[i], acc, false);
#else
#pragma unroll
  for (int i = 0; i < 4; i++) {
    const float2 wf = __half22float2(W.hh[i]);
    const float2 hf = __half22float2(H.hh[i]);
    acc = fmaf(wf.x, hf.x, acc);
    acc = fmaf(wf.y, hf.y, acc);
  }
#endif
  return acc;
}

// two independent accumulator chains per uint4 (breaks dep chains at 1 wave/SIMD)
__device__ __forceinline__ void dot8x2(uint4 wv, uint4 hv, float& a0, float& a1) {
  Pk16 W, H;
  W.u = wv; H.u = hv;
#if __has_builtin(__builtin_amdgcn_fdot2)
  a0 = __builtin_amdgcn_fdot2(W.h2[0], H.h2[0], a0, false);
  a1 = __builtin_amdgcn_fdot2(W.h2[1], H.h2[1], a1, false);
  a0 = __builtin_amdgcn_fdot2(W.h2[2], H.h2[2], a0, false);
  a1 = __builtin_amdgcn_fdot2(W.h2[3], H.h2[3], a1, false);
#else
#pragma unroll
  for (int i = 0; i < 4; i++) {
    const float2 wf = __half22float2(W.hh[i]);
    const float2 hf = __half22float2(H.hh[i]);
    float& a = (i & 1) ? a1 : a0;
    a = fmaf(wf.x, hf.x, a);
    a = fmaf(wf.y, hf.y, a);
  }
#endif
}

// ---------------------------------------------------------------------------
// generic f32 -> f16 converter (8 elems/thread)
// ---------------------------------------------------------------------------
__global__ __launch_bounds__(256) void cvt_h(const float* __restrict__ s,
                                             __half* __restrict__ d, int n8) {
  const int i = blockIdx.x * 256 + threadIdx.x;
  if (i >= n8) return;
  const float4 a = ((const float4*)s)[2 * i];
  const float4 b = ((const float4*)s)[2 * i + 1];
  union { __half h[8]; uint4 u; } o;
  o.h[0] = __float2half(a.x); o.h[1] = __float2half(a.y);
  o.h[2] = __float2half(a.z); o.h[3] = __float2half(a.w);
  o.h[4] = __float2half(b.x); o.h[5] = __float2half(b.y);
  o.h[6] = __float2half(b.z); o.h[7] = __float2half(b.w);
  ((uint4*)d)[i] = o.u;
}

// ---------------------------------------------------------------------------
// W_hh -> f16 transposed layout: WT[slice][k8][row][8] halfs (row = gate*256+j)
// ---------------------------------------------------------------------------
__global__ __launch_bounds__(256) void conv_w(const float* __restrict__ src,
                                              __half* __restrict__ dst) {
  const int s = blockIdx.y;
  const int idx = blockIdx.x * 256 + threadIdx.x;   // 0..32767
  const int j = idx & 1023;
  const int k8 = idx >> 10;
  const float* sp = src + (size_t)s * 262144 + (size_t)j * 256 + k8 * 8;
  const float4 a = *(const float4*)sp;
  const float4 b = *(const float4*)(sp + 4);
  union { __half h[8]; uint4 u; } o;
  o.h[0] = __float2half(a.x); o.h[1] = __float2half(a.y);
  o.h[2] = __float2half(a.z); o.h[3] = __float2half(a.w);
  o.h[4] = __float2half(b.x); o.h[5] = __float2half(b.y);
  o.h[6] = __float2half(b.z); o.h[7] = __float2half(b.w);
  *(uint4*)(dst + (size_t)s * 262144 + (size_t)k8 * 8192 + (size_t)j * 8) = o.u;
}

// ---------------------------------------------------------------------------
// MFMA f16 GEMM: xg[dir][m][n] = sum_k A[m][k]*W[dir][n][k] + bias[dir][n]
// ---------------------------------------------------------------------------
template <int DK, bool XL>
__global__ __launch_bounds__(256) void xg_gemm_h(const __half* __restrict__ A,
                                                 const __half* __restrict__ W,
                                                 const float* __restrict__ bias,
                                                 __half* __restrict__ xg) {
  const int dir = blockIdx.x >> 4;
  const int n0 = (blockIdx.x & 15) * 64;
  const int m0 = blockIdx.y * 64;
  const __half* Wd = W + (size_t)dir * (1024 * DK);
  const float* bd = bias + dir * 1024;
  __half* out = xg + (size_t)dir * (16384ull * 1024);

  __shared__ __align__(16) __half As[64][40];
  __shared__ __align__(16) __half Bs[64][40];

  const int tid = threadIdx.x;
  const int wave = tid >> 6, lane = tid & 63;
  const int fr = lane & 15, kg = lane >> 4;

  v4f acc[4];
#pragma unroll
  for (int i = 0; i < 4; i++) acc[i] = (v4f)(0.f);

  const int lr = tid >> 2;          // load row 0..63
  const int lc = (tid & 3) * 8;     // k offset
  size_t abase;
  if (XL) {
    const int m = m0 + lr, t = m >> 5, bb = m & 31;
    abase = ((size_t)(bb * 512 + t)) * DK + lc;
  } else {
    abase = (size_t)(m0 + lr) * DK + lc;
  }
  const size_t bbase = (size_t)(n0 + lr) * DK + lc;

  for (int k0 = 0; k0 < DK; k0 += 32) {
    *(uint4*)&As[lr][lc] = *(const uint4*)(A + abase + k0);
    *(uint4*)&Bs[lr][lc] = *(const uint4*)(Wd + bbase + k0);
    __syncthreads();
    const v8hf af = *(const v8hf*)&As[wave * 16 + fr][kg * 8];
#pragma unroll
    for (int nb = 0; nb < 4; ++nb) {
      const v8hf bf = *(const v8hf*)&Bs[nb * 16 + fr][kg * 8];
      acc[nb] = __builtin_amdgcn_mfma_f32_16x16x32_f16(af, bf, acc[nb], 0, 0, 0);
    }
    __syncthreads();
  }

#pragma unroll
  for (int nb = 0; nb < 4; ++nb) {
    const int n = n0 + nb * 16 + fr;
    const float bv = bd[n];
#pragma unroll
    for (int r = 0; r < 4; ++r) {
      const int m = m0 + wave * 16 + kg * 4 + r;
      out[(size_t)m * 1024 + n] = __float2half(acc[nb][r] + bv);
    }
  }
}

// ---------------------------------------------------------------------------
// LSTM layer v5: one WG per (dir,batch) chain; block 256 = 4 waves.
// Thread ju owns h-index ju and ALL 4 gate rows (full k=256 dot each).
// W residency: slices k8=0..7 in LDS (128 KB), k8=8..31 in VGPRs (96 uint4 =
// 384 VGPR; launch_bounds(256,1) allows up to 512). ZERO W streaming in loop.
// No gate exchange; ONE barrier per step; h double-buffered f16 in LDS.
// ---------------------------------------------------------------------------
__global__ __launch_bounds__(256, 1) void lstm_layer5(const __half* __restrict__ WT,
                                                      const __half* __restrict__ xg,
                                                      const int* __restrict__ lens,
                                                      __half* __restrict__ out) {
  const int w = blockIdx.x, dir = w >> 5, b = w & 31;
  const int ju = threadIdx.x;

  __shared__ __align__(16) __half Wc[8 * 1024 * 8];   // 128 KB, [k8][row][8]
  __shared__ __align__(16) __half h2[2][256];

  const uint4* __restrict__ Wt = (const uint4*)(WT + (size_t)dir * 262144);

  // LDS slices 0..7: flat copy of first 8192 uint4 (layout matches WT)
  uint4* wcp = (uint4*)Wc;
#pragma unroll
  for (int i = 0; i < 32; ++i)
    wcp[i * 256 + ju] = Wt[i * 256 + ju];

  // register slices 8..31: wr[s][g] = row (g*256+ju) of slice (8+s)
  uint4 wr[24][4];
#pragma unroll
  for (int s = 0; s < 24; ++s) {
#pragma unroll
    for (int g = 0; g < 4; ++g)
      wr[s][g] = Wt[(size_t)(8 + s) * 1024 + g * 256 + ju];
  }

  h2[0][ju] = __float2half(0.f);
  const int mylen = lens[b];
  float c = 0.f;

  const __half* xgb = xg + (size_t)dir * (512ull * 32 * 1024) + (size_t)b * 1024 + ju;
  int tt = dir ? (mylen - 1) : 0;
  const __half* xr0 = xgb + (size_t)tt * (32 * 1024);
  float p0 = __half2float(xr0[0]),   p1 = __half2float(xr0[256]);
  float p2 = __half2float(xr0[512]), p3 = __half2float(xr0[768]);
  __syncthreads();

#pragma unroll 1
  for (int t = 0; t < 512; ++t) {
    const int tcur = tt;
    const uint4* hp = (const uint4*)&h2[t & 1][0];
    float A0[4] = {0.f, 0.f, 0.f, 0.f};
    float A1[4] = {0.f, 0.f, 0.f, 0.f};

    // LDS-resident slices 0..7
#pragma unroll
    for (int s = 0; s < 8; ++s) {
      const uint4 hv = hp[s];
#pragma unroll
      for (int g = 0; g < 4; ++g) {
        const uint4 wv = wcp[(size_t)s * 1024 + g * 256 + ju];
        dot8x2(wv, hv, A0[g], A1[g]);
      }
    }
    // register-resident slices 8..31
#pragma unroll
    for (int s = 0; s < 24; ++s) {
      const uint4 hv = hp[8 + s];
#pragma unroll
      for (int g = 0; g < 4; ++g)
        dot8x2(wr[s][g], hv, A0[g], A1[g]);
    }

    const float g0 = A0[0] + A1[0] + p0;
    const float g1 = A0[1] + A1[1] + p1;
    const float g2 = A0[2] + A1[2] + p2;
    const float g3 = A0[3] + A1[3] + p3;

    if (t < 511) {
      const int tn = t + 1;
      tt = dir ? ((tn < mylen) ? (mylen - 1 - tn) : tn) : tn;
      const __half* xr = xgb + (size_t)tt * (32 * 1024);
      p0 = __half2float(xr[0]);   p1 = __half2float(xr[256]);
      p2 = __half2float(xr[512]); p3 = __half2float(xr[768]);
    }

    const float ig = sigmoidf_(g0);
    const float fg = sigmoidf_(g1);
    const float gg = tanhf_(g2);
    const float og = sigmoidf_(g3);
    c = fg * c + ig * gg;
    const float hnew = og * tanhf_(c);

    out[((size_t)tcur * 32 + b) * 512 + dir * 256 + ju] =
        __float2half((tcur < mylen) ? hnew : 0.f);
    h2[(t + 1) & 1][ju] = __float2half(hnew);
    __syncthreads();
  }
}

// ---------------------------------------------------------------------------
// emit[b][t][e] = softmax_e(out_row(t,b) . fc_w[e] + fc_b[e]); out is f16
// ---------------------------------------------------------------------------
__global__ __launch_bounds__(64) void emit_kernel(const __half* __restrict__ out,
                                                  const float* __restrict__ fcw,
                                                  const float* __restrict__ fcb,
                                                  float* __restrict__ emit) {
  __shared__ __align__(16) __half row[512];
  const int e = threadIdx.x;
  const int m = blockIdx.x;           // t*B + b
  const int b = m & 31, t = m >> 5;
  ((uint4*)row)[e] = ((const uint4*)(out + (size_t)m * 512))[e];
  __syncthreads();

  float acc = fcb[e];
  const float* we = fcw + (size_t)e * 512;
  const __half2* r2 = (const __half2*)row;
#pragma unroll 8
  for (int k = 0; k < 256; ++k) {
    const float2 h = __half22float2(r2[k]);
    const float2 wv = *(const float2*)(we + 2 * k);
    acc = fmaf(h.x, wv.x, fmaf(h.y, wv.y, acc));
  }
  float mx = acc;
  for (int off = 32; off; off >>= 1) mx = fmaxf(mx, __shfl_xor(mx, off));
  const float ex = __expf(acc - mx);
  float s = ex;
  for (int off = 32; off; off >>= 1) s += __shfl_xor(s, off);
  emit[((size_t)b * Ll + t) * Ee + e] = ex / s;
}

__global__ __launch_bounds__(256) void score_kernel(const float* __restrict__ emit,
                                                    const float* __restrict__ trans,
                                                    const int* __restrict__ tags,
                                                    const int* __restrict__ lens,
                                                    float* __restrict__ total) {
  const int b = blockIdx.x;
  const int len = lens[b];
  float part = 0.f;
  for (int t = threadIdx.x; t < len; t += 256) {
    const int tg = tags[b * Ll + t];
    float v = emit[((size_t)b * Ll + t) * Ee + tg];
    if (t >= 1) v += trans[tags[b * Ll + t - 1] * Ee + tg];
    part += v;
  }
  for (int off = 32; off; off >>= 1) part += __shfl_xor(part, off);
  __shared__ float wsum[4];
  if ((threadIdx.x & 63) == 0) wsum[threadIdx.x >> 6] = part;
  __syncthreads();
  if (threadIdx.x == 0) total[b] = wsum[0] + wsum[1] + wsum[2] + wsum[3];
}

// ---------------------------------------------------------------------------
// CRF prep: cm[j] = max_k trans[k][j]; E[j][k] = exp(trans[k][j] - cm[j])
// ---------------------------------------------------------------------------
__global__ __launch_bounds__(64) void crf_prep(const float* __restrict__ trans,
                                               float* __restrict__ E,
                                               float* __restrict__ cm) {
  const int j = threadIdx.x;
  float m = -1e30f;
  for (int k = 0; k < 64; k++) m = fmaxf(m, trans[k * 64 + j]);
  cm[j] = m;
  for (int k = 0; k < 64; k++) E[j * 64 + k] = __expf(trans[k * 64 + j] - m);
}

// ---------------------------------------------------------------------------
// CRF scan v2 (factorized): d_new[j] = log(sum_k e_k * E[j][k]) + maxd + cm[j]
// ---------------------------------------------------------------------------
__global__ __launch_bounds__(64) void crf_scan2(const float* __restrict__ emit,
                                                const float* __restrict__ E,
                                                const float* __restrict__ cm,
                                                const int* __restrict__ lens,
                                                float* __restrict__ dout) {
  const int b = blockIdx.x, j = threadIdx.x;
  __shared__ float el[2][64];
  float Er[64];
#pragma unroll
  for (int kc = 0; kc < 16; ++kc) {
    const float4 v = *(const float4*)(E + j * 64 + 4 * kc);
    Er[4 * kc + 0] = v.x; Er[4 * kc + 1] = v.y;
    Er[4 * kc + 2] = v.z; Er[4 * kc + 3] = v.w;
  }
  const float cmj = cm[j];
  const int len = lens[b];
  const float* eb = emit + (size_t)b * 512 * 64 + j;
  float d = eb[0];
  float enext = (len > 1) ? eb[64] : 0.f;

  for (int t = 1; t < len; ++t) {
    float m = d;
#pragma unroll
    for (int off = 32; off; off >>= 1) m = fmaxf(m, __shfl_xor(m, off));
    const float ej = __expf(d - m);
    el[t & 1][j] = ej;
    const float emt = enext;
    if (t + 1 < len) enext = eb[(size_t)(t + 1) * 64];
    __syncthreads();
    float s0 = 0.f, s1 = 0.f, s2 = 0.f, s3 = 0.f;
    const float4* e4 = (const float4*)&el[t & 1][0];
#pragma unroll
    for (int kc = 0; kc < 16; ++kc) {
      const float4 ev = e4[kc];
      s0 = fmaf(ev.x, Er[4 * kc + 0], s0);
      s1 = fmaf(ev.y, Er[4 * kc + 1], s1);
      s2 = fmaf(ev.z, Er[4 * kc + 2], s2);
      s3 = fmaf(ev.w, Er[4 * kc + 3], s3);
    }
    d = __logf((s0 + s1) + (s2 + s3)) + m + cmj + emt;
    __syncthreads();
  }
  dout[b * 64 + j] = d;
}

__global__ __launch_bounds__(64) void final_kernel(const float* __restrict__ dbuf,
                                                   const float* __restrict__ total,
                                                   const int* __restrict__ lens,
                                                   float* __restrict__ out) {
  const int j = threadIdx.x;
  float lsum = 0.f;
  for (int b = 0; b < 32; b++) {
    const float d = dbuf[b * 64 + j];
    float m = d;
    for (int off = 32; off; off >>= 1) m = fmaxf(m, __shfl_xor(m, off));
    const float e = __expf(d - m);
    float s = e;
    for (int off = 32; off; off >>= 1) s += __shfl_xor(s, off);
    const float Z = __logf(s) + m;
    if (j == 0) lsum += -(total[b] - Z) / (float)lens[b];
  }
  if (j == 0) out[0] = lsum / 32.f;
}

// ---------------------------------------------------------------------------
extern "C" void kernel_launch(void* const* d_in, const int* in_sizes, int n_in,
                              void* d_out, int out_size, void* d_ws, size_t ws_size,
                              hipStream_t stream) {
  const float* x = (const float*)d_in[0];
  const int* lens = (const int*)d_in[1];
  const int* tags = (const int*)d_in[2];
  const float* w_ih_l0 = (const float*)d_in[4];
  const float* w_hh_l0 = (const float*)d_in[5];
  const float* b_l0 = (const float*)d_in[6];
  const float* w_ih_l12 = (const float*)d_in[7];
  const float* w_hh_l12 = (const float*)d_in[8];
  const float* b_l12 = (const float*)d_in[9];
  const float* fc_w = (const float*)d_in[10];
  const float* fc_b = (const float*)d_in[11];
  const float* trans = (const float*)d_in[12];

  char* ws = (char*)d_ws;
  __half* xg = (__half*)ws;                          // 64 MiB
  __half* xh = (__half*)(ws + 67108864);             // 32 MiB
  __half* outA = (__half*)(ws + 100663296);          // 16 MiB
  __half* outB = (__half*)(ws + 117440512);          // 16 MiB
  __half* WT = (__half*)(ws + 134217728);            // 3 MiB
  __half* WIH0 = (__half*)(ws + 137363456);          // 4 MiB
  __half* WIH12 = (__half*)(ws + 141557760);         // 4 MiB
  float* Ebuf = (float*)(ws + 145752064);            // 16 KiB
  float* cmbuf = (float*)(ws + 145768448);           // 256 B
  // CRF buffers alias the (dead-by-then) xg region
  float* emit = (float*)ws;                          // 4 MiB
  float* total = (float*)(ws + 4194304);
  float* dbuf = total + 32;

  // one-time conversions + CRF prep
  cvt_h<<<8192, 256, 0, stream>>>(x, xh, 2097152);
  cvt_h<<<1024, 256, 0, stream>>>(w_ih_l0, WIH0, 262144);
  cvt_h<<<1024, 256, 0, stream>>>(w_ih_l12, WIH12, 262144);
  conv_w<<<dim3(128, 2), 256, 0, stream>>>(w_hh_l0, WT);
  conv_w<<<dim3(128, 4), 256, 0, stream>>>(w_hh_l12, WT + 2 * 262144);
  crf_prep<<<1, 64, 0, stream>>>(trans, Ebuf, cmbuf);

  const dim3 ggrid(32, 256);

  // layer 0
  xg_gemm_h<1024, true><<<ggrid, 256, 0, stream>>>(xh, WIH0, b_l0, xg);
  lstm_layer5<<<64, 256, 0, stream>>>(WT, xg, lens, outA);

  // layer 1
  xg_gemm_h<512, false><<<ggrid, 256, 0, stream>>>(outA, WIH12, b_l12, xg);
  lstm_layer5<<<64, 256, 0, stream>>>(WT + 2 * 262144, xg, lens, outB);

  // layer 2
  xg_gemm_h<512, false><<<ggrid, 256, 0, stream>>>(outB, WIH12 + 2 * 1024 * 512,
                                                   b_l12 + 2 * 1024, xg);
  lstm_layer5<<<64, 256, 0, stream>>>(WT + 4 * 262144, xg, lens, outA);

  // CRF
  emit_kernel<<<Ll * Bb, 64, 0, stream>>>(outA, fc_w, fc_b, emit);
  score_kernel<<<Bb, 256, 0, stream>>>(emit, trans, tags, lens, total);
  crf_scan2<<<Bb, 64, 0, stream>>>(emit, Ebuf, cmbuf, lens, dbuf);
  final_kernel<<<1, 64, 0, stream>>>(dbuf, total, lens, (float*)d_out);
}

// Round 7
// 3817.846 us; speedup vs baseline: 1.6166x; 1.6166x over previous
//
#include <hip/hip_runtime.h>
#include <hip/hip_fp16.h>

#define Bb 32
#define Ll 512
#define Dd 1024
#define Hh 256
#define Ee 64

__device__ __forceinline__ float sigmoidf_(float x) { return 1.f / (1.f + __expf(-x)); }
__device__ __forceinline__ float tanhf_(float x) { return 1.f - 2.f / (__expf(2.f * x) + 1.f); }

typedef _Float16 f16x2 __attribute__((ext_vector_type(2)));
typedef _Float16 v8hf __attribute__((ext_vector_type(8)));
typedef float v4f __attribute__((ext_vector_type(4)));
union Pk16 { uint4 u; f16x2 h2[4]; __half2 hh[4]; };

// two independent accumulator chains per uint4 (breaks dep chains)
__device__ __forceinline__ void dot8x2(uint4 wv, uint4 hv, float& a0, float& a1) {
  Pk16 W, H;
  W.u = wv; H.u = hv;
#if __has_builtin(__builtin_amdgcn_fdot2)
  a0 = __builtin_amdgcn_fdot2(W.h2[0], H.h2[0], a0, false);
  a1 = __builtin_amdgcn_fdot2(W.h2[1], H.h2[1], a1, false);
  a0 = __builtin_amdgcn_fdot2(W.h2[2], H.h2[2], a0, false);
  a1 = __builtin_amdgcn_fdot2(W.h2[3], H.h2[3], a1, false);
#else
#pragma unroll
  for (int i = 0; i < 4; i++) {
    const float2 wf = __half22float2(W.hh[i]);
    const float2 hf = __half22float2(H.hh[i]);
    float& a = (i & 1) ? a1 : a0;
    a = fmaf(wf.x, hf.x, a);
    a = fmaf(wf.y, hf.y, a);
  }
#endif
}

// ---------------------------------------------------------------------------
// generic f32 -> f16 converter (8 elems/thread)
// ---------------------------------------------------------------------------
__global__ __launch_bounds__(256) void cvt_h(const float* __restrict__ s,
                                             __half* __restrict__ d, int n8) {
  const int i = blockIdx.x * 256 + threadIdx.x;
  if (i >= n8) return;
  const float4 a = ((const float4*)s)[2 * i];
  const float4 b = ((const float4*)s)[2 * i + 1];
  union { __half h[8]; uint4 u; } o;
  o.h[0] = __float2half(a.x); o.h[1] = __float2half(a.y);
  o.h[2] = __float2half(a.z); o.h[3] = __float2half(a.w);
  o.h[4] = __float2half(b.x); o.h[5] = __float2half(b.y);
  o.h[6] = __float2half(b.z); o.h[7] = __float2half(b.w);
  ((uint4*)d)[i] = o.u;
}

// ---------------------------------------------------------------------------
// W_hh -> f16 transposed layout: WT[slice][k8][row][8] halfs (row = gate*256+j)
// ---------------------------------------------------------------------------
__global__ __launch_bounds__(256) void conv_w(const float* __restrict__ src,
                                              __half* __restrict__ dst) {
  const int s = blockIdx.y;
  const int idx = blockIdx.x * 256 + threadIdx.x;   // 0..32767
  const int j = idx & 1023;
  const int k8 = idx >> 10;
  const float* sp = src + (size_t)s * 262144 + (size_t)j * 256 + k8 * 8;
  const float4 a = *(const float4*)sp;
  const float4 b = *(const float4*)(sp + 4);
  union { __half h[8]; uint4 u; } o;
  o.h[0] = __float2half(a.x); o.h[1] = __float2half(a.y);
  o.h[2] = __float2half(a.z); o.h[3] = __float2half(a.w);
  o.h[4] = __float2half(b.x); o.h[5] = __float2half(b.y);
  o.h[6] = __float2half(b.z); o.h[7] = __float2half(b.w);
  *(uint4*)(dst + (size_t)s * 262144 + (size_t)k8 * 8192 + (size_t)j * 8) = o.u;
}

// ---------------------------------------------------------------------------
// MFMA f16 GEMM: xg[dir][m][n] = sum_k A[m][k]*W[dir][n][k] + bias[dir][n]
// ---------------------------------------------------------------------------
template <int DK, bool XL>
__global__ __launch_bounds__(256) void xg_gemm_h(const __half* __restrict__ A,
                                                 const __half* __restrict__ W,
                                                 const float* __restrict__ bias,
                                                 __half* __restrict__ xg) {
  const int dir = blockIdx.x >> 4;
  const int n0 = (blockIdx.x & 15) * 64;
  const int m0 = blockIdx.y * 64;
  const __half* Wd = W + (size_t)dir * (1024 * DK);
  const float* bd = bias + dir * 1024;
  __half* out = xg + (size_t)dir * (16384ull * 1024);

  __shared__ __align__(16) __half As[64][40];
  __shared__ __align__(16) __half Bs[64][40];

  const int tid = threadIdx.x;
  const int wave = tid >> 6, lane = tid & 63;
  const int fr = lane & 15, kg = lane >> 4;

  v4f acc[4];
#pragma unroll
  for (int i = 0; i < 4; i++) acc[i] = (v4f)(0.f);

  const int lr = tid >> 2;          // load row 0..63
  const int lc = (tid & 3) * 8;     // k offset
  size_t abase;
  if (XL) {
    const int m = m0 + lr, t = m >> 5, bb = m & 31;
    abase = ((size_t)(bb * 512 + t)) * DK + lc;
  } else {
    abase = (size_t)(m0 + lr) * DK + lc;
  }
  const size_t bbase = (size_t)(n0 + lr) * DK + lc;

  for (int k0 = 0; k0 < DK; k0 += 32) {
    *(uint4*)&As[lr][lc] = *(const uint4*)(A + abase + k0);
    *(uint4*)&Bs[lr][lc] = *(const uint4*)(Wd + bbase + k0);
    __syncthreads();
    const v8hf af = *(const v8hf*)&As[wave * 16 + fr][kg * 8];
#pragma unroll
    for (int nb = 0; nb < 4; ++nb) {
      const v8hf bf = *(const v8hf*)&Bs[nb * 16 + fr][kg * 8];
      acc[nb] = __builtin_amdgcn_mfma_f32_16x16x32_f16(af, bf, acc[nb], 0, 0, 0);
    }
    __syncthreads();
  }

#pragma unroll
  for (int nb = 0; nb < 4; ++nb) {
    const int n = n0 + nb * 16 + fr;
    const float bv = bd[n];
#pragma unroll
    for (int r = 0; r < 4; ++r) {
      const int m = m0 + wave * 16 + kg * 4 + r;
      out[(size_t)m * 1024 + n] = __float2half(acc[nb][r] + bv);
    }
  }
}

// ---------------------------------------------------------------------------
// LSTM layer v6: one WG per (dir,batch) chain; block 512 = 8 waves.
// tid = gh*256 + j. Thread owns gate rows (2gh, 2gh+1) for h-index j,
// full K=256 dot each. W residency: slices 0..8 LDS (144 KB), 9..29 in
// VGPRs (42 uint4 = 168 VGPR), 30..31 streamed (4 indep b128, issued early).
// Gate halves exchanged via 2 KB LDS; h double-buffered f16; 2 barriers/step.
// ---------------------------------------------------------------------------
__global__ __launch_bounds__(512, 1) void lstm_layer6(const __half* __restrict__ WT,
                                                      const __half* __restrict__ xg,
                                                      const int* __restrict__ lens,
                                                      __half* __restrict__ out) {
  const int w = blockIdx.x, dir = w >> 5, b = w & 31;
  const int tid = threadIdx.x, gh = tid >> 8, j = tid & 255;
  const int row0 = (2 * gh) * 256 + j;
  const int row1 = (2 * gh + 1) * 256 + j;

  __shared__ __align__(16) __half Wc[9 * 1024 * 8];   // 144 KB, [k8][row][8]
  __shared__ __align__(16) float aex[2][256];          // 2 KB
  __shared__ __align__(16) __half h2[2][256];          // 1 KB

  const uint4* __restrict__ Wt = (const uint4*)(WT + (size_t)dir * 262144);

  // LDS slices 0..8: 9216 uint4, 18 per thread
  uint4* wcp = (uint4*)Wc;
#pragma unroll
  for (int i = 0; i < 18; ++i)
    wcp[i * 512 + tid] = Wt[i * 512 + tid];

  // register slices 9..29
  uint4 wr0[21], wr1[21];
#pragma unroll
  for (int s = 0; s < 21; ++s) {
    wr0[s] = Wt[(size_t)(9 + s) * 1024 + row0];
    wr1[s] = Wt[(size_t)(9 + s) * 1024 + row1];
  }

  if (tid < 256) h2[0][tid] = __float2half(0.f);
  const int mylen = lens[b];
  float c = 0.f;

  // this thread's xg columns: gates 2gh, 2gh+1 at column j
  const __half* xgb = xg + (size_t)dir * (512ull * 32 * 1024) + (size_t)b * 1024 + j;
  int tt = dir ? (mylen - 1) : 0;
  float p0, p1;
  {
    const __half* xr = xgb + (size_t)tt * (32 * 1024);
    p0 = __half2float(xr[(2 * gh) * 256]);
    p1 = __half2float(xr[(2 * gh + 1) * 256]);
  }
  __syncthreads();

#pragma unroll 1
  for (int t = 0; t < 512; ++t) {
    const int tcur = tt;
    // streamed slices 30,31 — issue early, consume after the resident chains
    const uint4 s30r0 = Wt[30 * 1024 + row0];
    const uint4 s30r1 = Wt[30 * 1024 + row1];
    const uint4 s31r0 = Wt[31 * 1024 + row0];
    const uint4 s31r1 = Wt[31 * 1024 + row1];

    const uint4* hp = (const uint4*)&h2[t & 1][0];
    float A00 = 0.f, B00 = 0.f, A10 = 0.f, B10 = 0.f;

    // LDS-resident slices 0..8
#pragma unroll
    for (int s = 0; s < 9; ++s) {
      const uint4 hv = hp[s];
      dot8x2(wcp[(size_t)s * 1024 + row0], hv, A00, B00);
      dot8x2(wcp[(size_t)s * 1024 + row1], hv, A10, B10);
    }
    // register-resident slices 9..29
#pragma unroll
    for (int s = 0; s < 21; ++s) {
      const uint4 hv = hp[9 + s];
      dot8x2(wr0[s], hv, A00, B00);
      dot8x2(wr1[s], hv, A10, B10);
    }
    // streamed slices 30,31
    {
      const uint4 hv = hp[30];
      dot8x2(s30r0, hv, A00, B00);
      dot8x2(s30r1, hv, A10, B10);
    }
    {
      const uint4 hv = hp[31];
      dot8x2(s31r0, hv, A00, B00);
      dot8x2(s31r1, hv, A10, B10);
    }

    const float a0 = A00 + B00 + p0;   // preact of gate 2gh   (col j)
    const float a1 = A10 + B10 + p1;   // preact of gate 2gh+1 (col j)

    if (gh == 1) { aex[0][j] = a0; aex[1][j] = a1; }
    __syncthreads();
    if (gh == 0) {
      const float g0 = a0;            // i
      const float g1 = a1;            // f
      const float g2 = aex[0][j];     // g
      const float g3 = aex[1][j];     // o
      const float ig = sigmoidf_(g0);
      const float fg = sigmoidf_(g1);
      const float gg = tanhf_(g2);
      const float og = sigmoidf_(g3);
      c = fg * c + ig * gg;
      const float hnew = og * tanhf_(c);
      out[((size_t)tcur * 32 + b) * 512 + dir * 256 + j] =
          __float2half((tcur < mylen) ? hnew : 0.f);
      h2[(t + 1) & 1][j] = __float2half(hnew);
    }
    // prefetch next step's xg (both halves; no shared-mem touch)
    if (t < 511) {
      const int tn = t + 1;
      tt = dir ? ((tn < mylen) ? (mylen - 1 - tn) : tn) : tn;
      const __half* xr = xgb + (size_t)tt * (32 * 1024);
      p0 = __half2float(xr[(2 * gh) * 256]);
      p1 = __half2float(xr[(2 * gh + 1) * 256]);
    }
    __syncthreads();
  }
}

// ---------------------------------------------------------------------------
// emit[b][t][e] = softmax_e(out_row(t,b) . fc_w[e] + fc_b[e]); out is f16
// ---------------------------------------------------------------------------
__global__ __launch_bounds__(64) void emit_kernel(const __half* __restrict__ out,
                                                  const float* __restrict__ fcw,
                                                  const float* __restrict__ fcb,
                                                  float* __restrict__ emit) {
  __shared__ __align__(16) __half row[512];
  const int e = threadIdx.x;
  const int m = blockIdx.x;           // t*B + b
  const int b = m & 31, t = m >> 5;
  ((uint4*)row)[e] = ((const uint4*)(out + (size_t)m * 512))[e];
  __syncthreads();

  float acc = fcb[e];
  const float* we = fcw + (size_t)e * 512;
  const __half2* r2 = (const __half2*)row;
#pragma unroll 8
  for (int k = 0; k < 256; ++k) {
    const float2 h = __half22float2(r2[k]);
    const float2 wv = *(const float2*)(we + 2 * k);
    acc = fmaf(h.x, wv.x, fmaf(h.y, wv.y, acc));
  }
  float mx = acc;
  for (int off = 32; off; off >>= 1) mx = fmaxf(mx, __shfl_xor(mx, off));
  const float ex = __expf(acc - mx);
  float s = ex;
  for (int off = 32; off; off >>= 1) s += __shfl_xor(s, off);
  emit[((size_t)b * Ll + t) * Ee + e] = ex / s;
}

__global__ __launch_bounds__(256) void score_kernel(const float* __restrict__ emit,
                                                    const float* __restrict__ trans,
                                                    const int* __restrict__ tags,
                                                    const int* __restrict__ lens,
                                                    float* __restrict__ total) {
  const int b = blockIdx.x;
  const int len = lens[b];
  float part = 0.f;
  for (int t = threadIdx.x; t < len; t += 256) {
    const int tg = tags[b * Ll + t];
    float v = emit[((size_t)b * Ll + t) * Ee + tg];
    if (t >= 1) v += trans[tags[b * Ll + t - 1] * Ee + tg];
    part += v;
  }
  for (int off = 32; off; off >>= 1) part += __shfl_xor(part, off);
  __shared__ float wsum[4];
  if ((threadIdx.x & 63) == 0) wsum[threadIdx.x >> 6] = part;
  __syncthreads();
  if (threadIdx.x == 0) total[b] = wsum[0] + wsum[1] + wsum[2] + wsum[3];
}

// ---------------------------------------------------------------------------
// CRF prep: cm[j] = max_k trans[k][j]; E[j][k] = exp(trans[k][j] - cm[j])
// ---------------------------------------------------------------------------
__global__ __launch_bounds__(64) void crf_prep(const float* __restrict__ trans,
                                               float* __restrict__ E,
                                               float* __restrict__ cm) {
  const int j = threadIdx.x;
  float m = -1e30f;
  for (int k = 0; k < 64; k++) m = fmaxf(m, trans[k * 64 + j]);
  cm[j] = m;
  for (int k = 0; k < 64; k++) E[j * 64 + k] = __expf(trans[k * 64 + j] - m);
}

// ---------------------------------------------------------------------------
// CRF scan v2 (factorized): d_new[j] = log(sum_k e_k * E[j][k]) + maxd + cm[j]
// ---------------------------------------------------------------------------
__global__ __launch_bounds__(64) void crf_scan2(const float* __restrict__ emit,
                                                const float* __restrict__ E,
                                                const float* __restrict__ cm,
                                                const int* __restrict__ lens,
                                                float* __restrict__ dout) {
  const int b = blockIdx.x, j = threadIdx.x;
  __shared__ float el[2][64];
  float Er[64];
#pragma unroll
  for (int kc = 0; kc < 16; ++kc) {
    const float4 v = *(const float4*)(E + j * 64 + 4 * kc);
    Er[4 * kc + 0] = v.x; Er[4 * kc + 1] = v.y;
    Er[4 * kc + 2] = v.z; Er[4 * kc + 3] = v.w;
  }
  const float cmj = cm[j];
  const int len = lens[b];
  const float* eb = emit + (size_t)b * 512 * 64 + j;
  float d = eb[0];
  float enext = (len > 1) ? eb[64] : 0.f;

  for (int t = 1; t < len; ++t) {
    float m = d;
#pragma unroll
    for (int off = 32; off; off >>= 1) m = fmaxf(m, __shfl_xor(m, off));
    const float ej = __expf(d - m);
    el[t & 1][j] = ej;
    const float emt = enext;
    if (t + 1 < len) enext = eb[(size_t)(t + 1) * 64];
    __syncthreads();
    float s0 = 0.f, s1 = 0.f, s2 = 0.f, s3 = 0.f;
    const float4* e4 = (const float4*)&el[t & 1][0];
#pragma unroll
    for (int kc = 0; kc < 16; ++kc) {
      const float4 ev = e4[kc];
      s0 = fmaf(ev.x, Er[4 * kc + 0], s0);
      s1 = fmaf(ev.y, Er[4 * kc + 1], s1);
      s2 = fmaf(ev.z, Er[4 * kc + 2], s2);
      s3 = fmaf(ev.w, Er[4 * kc + 3], s3);
    }
    d = __logf((s0 + s1) + (s2 + s3)) + m + cmj + emt;
    __syncthreads();
  }
  dout[b * 64 + j] = d;
}

__global__ __launch_bounds__(64) void final_kernel(const float* __restrict__ dbuf,
                                                   const float* __restrict__ total,
                                                   const int* __restrict__ lens,
                                                   float* __restrict__ out) {
  const int j = threadIdx.x;
  float lsum = 0.f;
  for (int b = 0; b < 32; b++) {
    const float d = dbuf[b * 64 + j];
    float m = d;
    for (int off = 32; off; off >>= 1) m = fmaxf(m, __shfl_xor(m, off));
    const float e = __expf(d - m);
    float s = e;
    for (int off = 32; off; off >>= 1) s += __shfl_xor(s, off);
    const float Z = __logf(s) + m;
    if (j == 0) lsum += -(total[b] - Z) / (float)lens[b];
  }
  if (j == 0) out[0] = lsum / 32.f;
}

// ---------------------------------------------------------------------------
extern "C" void kernel_launch(void* const* d_in, const int* in_sizes, int n_in,
                              void* d_out, int out_size, void* d_ws, size_t ws_size,
                              hipStream_t stream) {
  const float* x = (const float*)d_in[0];
  const int* lens = (const int*)d_in[1];
  const int* tags = (const int*)d_in[2];
  const float* w_ih_l0 = (const float*)d_in[4];
  const float* w_hh_l0 = (const float*)d_in[5];
  const float* b_l0 = (const float*)d_in[6];
  const float* w_ih_l12 = (const float*)d_in[7];
  const float* w_hh_l12 = (const float*)d_in[8];
  const float* b_l12 = (const float*)d_in[9];
  const float* fc_w = (const float*)d_in[10];
  const float* fc_b = (const float*)d_in[11];
  const float* trans = (const float*)d_in[12];

  char* ws = (char*)d_ws;
  __half* xg = (__half*)ws;                          // 64 MiB
  __half* xh = (__half*)(ws + 67108864);             // 32 MiB
  __half* outA = (__half*)(ws + 100663296);          // 16 MiB
  __half* outB = (__half*)(ws + 117440512);          // 16 MiB
  __half* WT = (__half*)(ws + 134217728);            // 3 MiB
  __half* WIH0 = (__half*)(ws + 137363456);          // 4 MiB
  __half* WIH12 = (__half*)(ws + 141557760);         // 4 MiB
  float* Ebuf = (float*)(ws + 145752064);            // 16 KiB
  float* cmbuf = (float*)(ws + 145768448);           // 256 B
  // CRF buffers alias the (dead-by-then) xg region
  float* emit = (float*)ws;                          // 4 MiB
  float* total = (float*)(ws + 4194304);
  float* dbuf = total + 32;

  // one-time conversions + CRF prep
  cvt_h<<<8192, 256, 0, stream>>>(x, xh, 2097152);
  cvt_h<<<1024, 256, 0, stream>>>(w_ih_l0, WIH0, 262144);
  cvt_h<<<1024, 256, 0, stream>>>(w_ih_l12, WIH12, 262144);
  conv_w<<<dim3(128, 2), 256, 0, stream>>>(w_hh_l0, WT);
  conv_w<<<dim3(128, 4), 256, 0, stream>>>(w_hh_l12, WT + 2 * 262144);
  crf_prep<<<1, 64, 0, stream>>>(trans, Ebuf, cmbuf);

  const dim3 ggrid(32, 256);

  // layer 0
  xg_gemm_h<1024, true><<<ggrid, 256, 0, stream>>>(xh, WIH0, b_l0, xg);
  lstm_layer6<<<64, 512, 0, stream>>>(WT, xg, lens, outA);

  // layer 1
  xg_gemm_h<512, false><<<ggrid, 256, 0, stream>>>(outA, WIH12, b_l12, xg);
  lstm_layer6<<<64, 512, 0, stream>>>(WT + 2 * 262144, xg, lens, outB);

  // layer 2
  xg_gemm_h<512, false><<<ggrid, 256, 0, stream>>>(outB, WIH12 + 2 * 1024 * 512,
                                                   b_l12 + 2 * 1024, xg);
  lstm_layer6<<<64, 512, 0, stream>>>(WT + 4 * 262144, xg, lens, outA);

  // CRF
  emit_kernel<<<Ll * Bb, 64, 0, stream>>>(outA, fc_w, fc_b, emit);
  score_kernel<<<Bb, 256, 0, stream>>>(emit, trans, tags, lens, total);
  crf_scan2<<<Bb, 64, 0, stream>>>(emit, Ebuf, cmbuf, lens, dbuf);
  final_kernel<<<1, 64, 0, stream>>>(dbuf, total, lens, (float*)d_out);
}

// Round 8
// 3101.683 us; speedup vs baseline: 1.9899x; 1.2309x over previous
//
#include <hip/hip_runtime.h>
#include <hip/hip_fp16.h>

#define Bb 32
#define Ll 512
#define Dd 1024
#define Hh 256
#define Ee 64

__device__ __forceinline__ float sigmoidf_(float x) { return 1.f / (1.f + __expf(-x)); }
__device__ __forceinline__ float tanhf_(float x) { return 1.f - 2.f / (__expf(2.f * x) + 1.f); }

typedef _Float16 v8hf __attribute__((ext_vector_type(8)));
typedef float v4f __attribute__((ext_vector_type(4)));

__device__ __forceinline__ int sdot4_(unsigned int a, unsigned int b, int acc) {
#if __has_builtin(__builtin_amdgcn_sdot4)
  return __builtin_amdgcn_sdot4((int)a, (int)b, acc, false);
#else
  int r = acc;
#pragma unroll
  for (int i = 0; i < 4; i++)
    r += (((int)a << (24 - 8 * i)) >> 24) * (((int)b << (24 - 8 * i)) >> 24);
  return r;
#endif
}

// ---------------------------------------------------------------------------
// generic f32 -> f16 converter (8 elems/thread)
// ---------------------------------------------------------------------------
__global__ __launch_bounds__(256) void cvt_h(const float* __restrict__ s,
                                             __half* __restrict__ d, int n8) {
  const int i = blockIdx.x * 256 + threadIdx.x;
  if (i >= n8) return;
  const float4 a = ((const float4*)s)[2 * i];
  const float4 b = ((const float4*)s)[2 * i + 1];
  union { __half h[8]; uint4 u; } o;
  o.h[0] = __float2half(a.x); o.h[1] = __float2half(a.y);
  o.h[2] = __float2half(a.z); o.h[3] = __float2half(a.w);
  o.h[4] = __float2half(b.x); o.h[5] = __float2half(b.y);
  o.h[6] = __float2half(b.z); o.h[7] = __float2half(b.w);
  ((uint4*)d)[i] = o.u;
}

// ---------------------------------------------------------------------------
// W_hh -> int8 transposed layout: WQ[slice][k8][row] as uint2 (8 bytes = 8 k)
// q = clamp(round(w * 2048), -127, 127);  row = gate*256 + j
// ---------------------------------------------------------------------------
__global__ __launch_bounds__(256) void conv_wq(const float* __restrict__ src,
                                               uint2* __restrict__ dst) {
  const int s = blockIdx.y;
  const int idx = blockIdx.x * 256 + threadIdx.x;   // 0..32767
  const int j = idx & 1023;
  const int k8 = idx >> 10;
  const float* sp = src + (size_t)s * 262144 + (size_t)j * 256 + k8 * 8;
  const float4 a = *(const float4*)sp;
  const float4 b = *(const float4*)(sp + 4);
  const float v[8] = {a.x, a.y, a.z, a.w, b.x, b.y, b.z, b.w};
  unsigned int lo = 0, hi = 0;
#pragma unroll
  for (int i = 0; i < 8; i++) {
    int q = (int)rintf(v[i] * 2048.f);
    q = max(-127, min(127, q));
    const unsigned int u = (unsigned int)(q & 0xFF);
    if (i < 4) lo |= u << (8 * i); else hi |= u << (8 * (i - 4));
  }
  dst[(size_t)s * 32768 + (size_t)k8 * 1024 + j] = make_uint2(lo, hi);
}

// ---------------------------------------------------------------------------
// MFMA f16 GEMM: xg[dir][m][n] = sum_k A[m][k]*W[dir][n][k] + bias[dir][n]
// ---------------------------------------------------------------------------
template <int DK, bool XL>
__global__ __launch_bounds__(256) void xg_gemm_h(const __half* __restrict__ A,
                                                 const __half* __restrict__ W,
                                                 const float* __restrict__ bias,
                                                 __half* __restrict__ xg) {
  const int dir = blockIdx.x >> 4;
  const int n0 = (blockIdx.x & 15) * 64;
  const int m0 = blockIdx.y * 64;
  const __half* Wd = W + (size_t)dir * (1024 * DK);
  const float* bd = bias + dir * 1024;
  __half* out = xg + (size_t)dir * (16384ull * 1024);

  __shared__ __align__(16) __half As[64][40];
  __shared__ __align__(16) __half Bs[64][40];

  const int tid = threadIdx.x;
  const int wave = tid >> 6, lane = tid & 63;
  const int fr = lane & 15, kg = lane >> 4;

  v4f acc[4];
#pragma unroll
  for (int i = 0; i < 4; i++) acc[i] = (v4f)(0.f);

  const int lr = tid >> 2;          // load row 0..63
  const int lc = (tid & 3) * 8;     // k offset
  size_t abase;
  if (XL) {
    const int m = m0 + lr, t = m >> 5, bb = m & 31;
    abase = ((size_t)(bb * 512 + t)) * DK + lc;
  } else {
    abase = (size_t)(m0 + lr) * DK + lc;
  }
  const size_t bbase = (size_t)(n0 + lr) * DK + lc;

  for (int k0 = 0; k0 < DK; k0 += 32) {
    *(uint4*)&As[lr][lc] = *(const uint4*)(A + abase + k0);
    *(uint4*)&Bs[lr][lc] = *(const uint4*)(Wd + bbase + k0);
    __syncthreads();
    const v8hf af = *(const v8hf*)&As[wave * 16 + fr][kg * 8];
#pragma unroll
    for (int nb = 0; nb < 4; ++nb) {
      const v8hf bf = *(const v8hf*)&Bs[nb * 16 + fr][kg * 8];
      acc[nb] = __builtin_amdgcn_mfma_f32_16x16x32_f16(af, bf, acc[nb], 0, 0, 0);
    }
    __syncthreads();
  }

#pragma unroll
  for (int nb = 0; nb < 4; ++nb) {
    const int n = n0 + nb * 16 + fr;
    const float bv = bd[n];
#pragma unroll
    for (int r = 0; r < 4; ++r) {
      const int m = m0 + wave * 16 + kg * 4 + r;
      out[(size_t)m * 1024 + n] = __float2half(acc[nb][r] + bv);
    }
  }
}

// ---------------------------------------------------------------------------
// LSTM layer v8 (int8): one WG per (dir,batch) chain; block 512 = 8 waves.
// tid = gh*256 + j; thread owns gate rows (2gh, 2gh+1) for h-index j.
// W int8 (scale 2048): slices 0..17 LDS-resident (144 KB), 18..31 streamed
// from L2 (112 KB/step). h int8 (scale 127) double-buffered in LDS (64 B).
// Dot via v_dot4_i32_i8; preact = (i32 dot) / (2048*127) + xg(f16).
// ---------------------------------------------------------------------------
__global__ __launch_bounds__(512, 1) void lstm_layer8(const uint2* __restrict__ WQ,
                                                      const __half* __restrict__ xg,
                                                      const int* __restrict__ lens,
                                                      __half* __restrict__ out) {
  const int w = blockIdx.x, dir = w >> 5, b = w & 31;
  const int tid = threadIdx.x, gh = tid >> 8, j = tid & 255;
  const int row0 = (2 * gh) * 256 + j;
  const int row1 = (2 * gh + 1) * 256 + j;

  __shared__ __align__(16) uint2 Wc8[18 * 1024];   // 144 KB
  __shared__ __align__(16) uint2 hq2[2][32];       // 512 B
  __shared__ __align__(16) float aex[2][256];      // 2 KB

  const uint2* __restrict__ Wt = WQ + (size_t)dir * 32768;

  // LDS slices 0..17: 18432 uint2, 36 per thread
#pragma unroll
  for (int i = 0; i < 36; ++i)
    Wc8[i * 512 + tid] = Wt[i * 512 + tid];

  if (tid < 32) hq2[0][tid] = make_uint2(0u, 0u);
  const int mylen = lens[b];
  float c = 0.f;

  const __half* xgb = xg + (size_t)dir * (512ull * 32 * 1024) + (size_t)b * 1024 + j;
  int tt = dir ? (mylen - 1) : 0;
  float p0, p1;
  {
    const __half* xr = xgb + (size_t)tt * (32 * 1024);
    p0 = __half2float(xr[(2 * gh) * 256]);
    p1 = __half2float(xr[(2 * gh + 1) * 256]);
  }
  __syncthreads();

#pragma unroll 1
  for (int t = 0; t < 512; ++t) {
    const int tcur = tt;
    const uint2* hq = &hq2[t & 1][0];
    int A0 = 0, B0 = 0, A1 = 0, B1 = 0;

    // LDS-resident slices 0..17
#pragma unroll
    for (int s = 0; s < 18; ++s) {
      const uint2 hv = hq[s];
      const uint2 w0 = Wc8[s * 1024 + row0];
      const uint2 w1 = Wc8[s * 1024 + row1];
      A0 = sdot4_(w0.x, hv.x, A0); B0 = sdot4_(w0.y, hv.y, B0);
      A1 = sdot4_(w1.x, hv.x, A1); B1 = sdot4_(w1.y, hv.y, B1);
    }
    // streamed slices 18..31
#pragma unroll
    for (int s = 18; s < 32; ++s) {
      const uint2 hv = hq[s];
      const uint2 w0 = Wt[(size_t)s * 1024 + row0];
      const uint2 w1 = Wt[(size_t)s * 1024 + row1];
      A0 = sdot4_(w0.x, hv.x, A0); B0 = sdot4_(w0.y, hv.y, B0);
      A1 = sdot4_(w1.x, hv.x, A1); B1 = sdot4_(w1.y, hv.y, B1);
    }

    const float a0 = (float)(A0 + B0) * 3.844734e-6f + p0;  // 1/(2048*127)
    const float a1 = (float)(A1 + B1) * 3.844734e-6f + p1;

    if (gh == 1) { aex[0][j] = a0; aex[1][j] = a1; }
    __syncthreads();
    if (gh == 0) {
      const float ig = sigmoidf_(a0);
      const float fg = sigmoidf_(a1);
      const float gg = tanhf_(aex[0][j]);
      const float og = sigmoidf_(aex[1][j]);
      c = fg * c + ig * gg;
      const float hnew = og * tanhf_(c);
      out[((size_t)tcur * 32 + b) * 512 + dir * 256 + j] =
          __float2half((tcur < mylen) ? hnew : 0.f);
      const int q = (int)rintf(hnew * 127.f);
      ((signed char*)&hq2[(t + 1) & 1][0])[j] = (signed char)q;
    }
    if (t < 511) {
      const int tn = t + 1;
      tt = dir ? ((tn < mylen) ? (mylen - 1 - tn) : tn) : tn;
      const __half* xr = xgb + (size_t)tt * (32 * 1024);
      p0 = __half2float(xr[(2 * gh) * 256]);
      p1 = __half2float(xr[(2 * gh + 1) * 256]);
    }
    __syncthreads();
  }
}

// ---------------------------------------------------------------------------
// emit[b][t][e] = softmax_e(out_row(t,b) . fc_w[e] + fc_b[e]); out is f16
// ---------------------------------------------------------------------------
__global__ __launch_bounds__(64) void emit_kernel(const __half* __restrict__ out,
                                                  const float* __restrict__ fcw,
                                                  const float* __restrict__ fcb,
                                                  float* __restrict__ emit) {
  __shared__ __align__(16) __half row[512];
  const int e = threadIdx.x;
  const int m = blockIdx.x;           // t*B + b
  const int b = m & 31, t = m >> 5;
  ((uint4*)row)[e] = ((const uint4*)(out + (size_t)m * 512))[e];
  __syncthreads();

  float acc = fcb[e];
  const float* we = fcw + (size_t)e * 512;
  const __half2* r2 = (const __half2*)row;
#pragma unroll 8
  for (int k = 0; k < 256; ++k) {
    const float2 h = __half22float2(r2[k]);
    const float2 wv = *(const float2*)(we + 2 * k);
    acc = fmaf(h.x, wv.x, fmaf(h.y, wv.y, acc));
  }
  float mx = acc;
  for (int off = 32; off; off >>= 1) mx = fmaxf(mx, __shfl_xor(mx, off));
  const float ex = __expf(acc - mx);
  float s = ex;
  for (int off = 32; off; off >>= 1) s += __shfl_xor(s, off);
  emit[((size_t)b * Ll + t) * Ee + e] = ex / s;
}

__global__ __launch_bounds__(256) void score_kernel(const float* __restrict__ emit,
                                                    const float* __restrict__ trans,
                                                    const int* __restrict__ tags,
                                                    const int* __restrict__ lens,
                                                    float* __restrict__ total) {
  const int b = blockIdx.x;
  const int len = lens[b];
  float part = 0.f;
  for (int t = threadIdx.x; t < len; t += 256) {
    const int tg = tags[b * Ll + t];
    float v = emit[((size_t)b * Ll + t) * Ee + tg];
    if (t >= 1) v += trans[tags[b * Ll + t - 1] * Ee + tg];
    part += v;
  }
  for (int off = 32; off; off >>= 1) part += __shfl_xor(part, off);
  __shared__ float wsum[4];
  if ((threadIdx.x & 63) == 0) wsum[threadIdx.x >> 6] = part;
  __syncthreads();
  if (threadIdx.x == 0) total[b] = wsum[0] + wsum[1] + wsum[2] + wsum[3];
}

// ---------------------------------------------------------------------------
// CRF prep: cm[j] = max_k trans[k][j]; E[j][k] = exp(trans[k][j] - cm[j])
// ---------------------------------------------------------------------------
__global__ __launch_bounds__(64) void crf_prep(const float* __restrict__ trans,
                                               float* __restrict__ E,
                                               float* __restrict__ cm) {
  const int j = threadIdx.x;
  float m = -1e30f;
  for (int k = 0; k < 64; k++) m = fmaxf(m, trans[k * 64 + j]);
  cm[j] = m;
  for (int k = 0; k < 64; k++) E[j * 64 + k] = __expf(trans[k * 64 + j] - m);
}

// ---------------------------------------------------------------------------
// CRF scan v2 (factorized): d_new[j] = log(sum_k e_k * E[j][k]) + maxd + cm[j]
// ---------------------------------------------------------------------------
__global__ __launch_bounds__(64) void crf_scan2(const float* __restrict__ emit,
                                                const float* __restrict__ E,
                                                const float* __restrict__ cm,
                                                const int* __restrict__ lens,
                                                float* __restrict__ dout) {
  const int b = blockIdx.x, j = threadIdx.x;
  __shared__ float el[2][64];
  float Er[64];
#pragma unroll
  for (int kc = 0; kc < 16; ++kc) {
    const float4 v = *(const float4*)(E + j * 64 + 4 * kc);
    Er[4 * kc + 0] = v.x; Er[4 * kc + 1] = v.y;
    Er[4 * kc + 2] = v.z; Er[4 * kc + 3] = v.w;
  }
  const float cmj = cm[j];
  const int len = lens[b];
  const float* eb = emit + (size_t)b * 512 * 64 + j;
  float d = eb[0];
  float enext = (len > 1) ? eb[64] : 0.f;

  for (int t = 1; t < len; ++t) {
    float m = d;
#pragma unroll
    for (int off = 32; off; off >>= 1) m = fmaxf(m, __shfl_xor(m, off));
    const float ej = __expf(d - m);
    el[t & 1][j] = ej;
    const float emt = enext;
    if (t + 1 < len) enext = eb[(size_t)(t + 1) * 64];
    __syncthreads();
    float s0 = 0.f, s1 = 0.f, s2 = 0.f, s3 = 0.f;
    const float4* e4 = (const float4*)&el[t & 1][0];
#pragma unroll
    for (int kc = 0; kc < 16; ++kc) {
      const float4 ev = e4[kc];
      s0 = fmaf(ev.x, Er[4 * kc + 0], s0);
      s1 = fmaf(ev.y, Er[4 * kc + 1], s1);
      s2 = fmaf(ev.z, Er[4 * kc + 2], s2);
      s3 = fmaf(ev.w, Er[4 * kc + 3], s3);
    }
    d = __logf((s0 + s1) + (s2 + s3)) + m + cmj + emt;
    __syncthreads();
  }
  dout[b * 64 + j] = d;
}

__global__ __launch_bounds__(64) void final_kernel(const float* __restrict__ dbuf,
                                                   const float* __restrict__ total,
                                                   const int* __restrict__ lens,
                                                   float* __restrict__ out) {
  const int j = threadIdx.x;
  float lsum = 0.f;
  for (int b = 0; b < 32; b++) {
    const float d = dbuf[b * 64 + j];
    float m = d;
    for (int off = 32; off; off >>= 1) m = fmaxf(m, __shfl_xor(m, off));
    const float e = __expf(d - m);
    float s = e;
    for (int off = 32; off; off >>= 1) s += __shfl_xor(s, off);
    const float Z = __logf(s) + m;
    if (j == 0) lsum += -(total[b] - Z) / (float)lens[b];
  }
  if (j == 0) out[0] = lsum / 32.f;
}

// ---------------------------------------------------------------------------
extern "C" void kernel_launch(void* const* d_in, const int* in_sizes, int n_in,
                              void* d_out, int out_size, void* d_ws, size_t ws_size,
                              hipStream_t stream) {
  const float* x = (const float*)d_in[0];
  const int* lens = (const int*)d_in[1];
  const int* tags = (const int*)d_in[2];
  const float* w_ih_l0 = (const float*)d_in[4];
  const float* w_hh_l0 = (const float*)d_in[5];
  const float* b_l0 = (const float*)d_in[6];
  const float* w_ih_l12 = (const float*)d_in[7];
  const float* w_hh_l12 = (const float*)d_in[8];
  const float* b_l12 = (const float*)d_in[9];
  const float* fc_w = (const float*)d_in[10];
  const float* fc_b = (const float*)d_in[11];
  const float* trans = (const float*)d_in[12];

  char* ws = (char*)d_ws;
  __half* xg = (__half*)ws;                          // 64 MiB
  __half* xh = (__half*)(ws + 67108864);             // 32 MiB
  __half* outA = (__half*)(ws + 100663296);          // 16 MiB
  __half* outB = (__half*)(ws + 117440512);          // 16 MiB
  uint2* WQ = (uint2*)(ws + 134217728);              // 1.5 MiB (whh int8)
  __half* WIH0 = (__half*)(ws + 137363456);          // 4 MiB
  __half* WIH12 = (__half*)(ws + 141557760);         // 4 MiB
  float* Ebuf = (float*)(ws + 145752064);            // 16 KiB
  float* cmbuf = (float*)(ws + 145768448);           // 256 B
  // CRF buffers alias the (dead-by-then) xg region
  float* emit = (float*)ws;                          // 4 MiB
  float* total = (float*)(ws + 4194304);
  float* dbuf = total + 32;

  // one-time conversions + CRF prep
  cvt_h<<<8192, 256, 0, stream>>>(x, xh, 2097152);
  cvt_h<<<1024, 256, 0, stream>>>(w_ih_l0, WIH0, 262144);
  cvt_h<<<1024, 256, 0, stream>>>(w_ih_l12, WIH12, 262144);
  conv_wq<<<dim3(128, 2), 256, 0, stream>>>(w_hh_l0, WQ);
  conv_wq<<<dim3(128, 4), 256, 0, stream>>>(w_hh_l12, WQ + 2 * 32768);
  crf_prep<<<1, 64, 0, stream>>>(trans, Ebuf, cmbuf);

  const dim3 ggrid(32, 256);

  // layer 0
  xg_gemm_h<1024, true><<<ggrid, 256, 0, stream>>>(xh, WIH0, b_l0, xg);
  lstm_layer8<<<64, 512, 0, stream>>>(WQ, xg, lens, outA);

  // layer 1
  xg_gemm_h<512, false><<<ggrid, 256, 0, stream>>>(outA, WIH12, b_l12, xg);
  lstm_layer8<<<64, 512, 0, stream>>>(WQ + 2 * 32768, xg, lens, outB);

  // layer 2
  xg_gemm_h<512, false><<<ggrid, 256, 0, stream>>>(outB, WIH12 + 2 * 1024 * 512,
                                                   b_l12 + 2 * 1024, xg);
  lstm_layer8<<<64, 512, 0, stream>>>(WQ + 4 * 32768, xg, lens, outA);

  // CRF
  emit_kernel<<<Ll * Bb, 64, 0, stream>>>(outA, fc_w, fc_b, emit);
  score_kernel<<<Bb, 256, 0, stream>>>(emit, trans, tags, lens, total);
  crf_scan2<<<Bb, 64, 0, stream>>>(emit, Ebuf, cmbuf, lens, dbuf);
  final_kernel<<<1, 64, 0, stream>>>(dbuf, total, lens, (float*)d_out);
}

// Round 9
// 2803.895 us; speedup vs baseline: 2.2013x; 1.1062x over previous
//
#include <hip/hip_runtime.h>
#include <hip/hip_fp16.h>

#define Bb 32
#define Ll 512
#define Dd 1024
#define Hh 256
#define Ee 64

__device__ __forceinline__ float sigmoidf_(float x) { return 1.f / (1.f + __expf(-x)); }
__device__ __forceinline__ float tanhf_(float x) { return 1.f - 2.f / (__expf(2.f * x) + 1.f); }

typedef _Float16 v8hf __attribute__((ext_vector_type(8)));
typedef float v4f __attribute__((ext_vector_type(4)));

__device__ __forceinline__ int sdot4_(unsigned int a, unsigned int b, int acc) {
#if __has_builtin(__builtin_amdgcn_sdot4)
  return __builtin_amdgcn_sdot4((int)a, (int)b, acc, false);
#else
  int r = acc;
#pragma unroll
  for (int i = 0; i < 4; i++)
    r += (((int)a << (24 - 8 * i)) >> 24) * (((int)b << (24 - 8 * i)) >> 24);
  return r;
#endif
}

// dot a full 16-byte chunk into two accumulators
__device__ __forceinline__ void dotc(uint4 wv, uint4 hv, int& a, int& b) {
  a = sdot4_(wv.x, hv.x, a);
  b = sdot4_(wv.y, hv.y, b);
  a = sdot4_(wv.z, hv.z, a);
  b = sdot4_(wv.w, hv.w, b);
}

// ---------------------------------------------------------------------------
// generic f32 -> f16 converter (8 elems/thread)
// ---------------------------------------------------------------------------
__global__ __launch_bounds__(256) void cvt_h(const float* __restrict__ s,
                                             __half* __restrict__ d, int n8) {
  const int i = blockIdx.x * 256 + threadIdx.x;
  if (i >= n8) return;
  const float4 a = ((const float4*)s)[2 * i];
  const float4 b = ((const float4*)s)[2 * i + 1];
  union { __half h[8]; uint4 u; } o;
  o.h[0] = __float2half(a.x); o.h[1] = __float2half(a.y);
  o.h[2] = __float2half(a.z); o.h[3] = __float2half(a.w);
  o.h[4] = __float2half(b.x); o.h[5] = __float2half(b.y);
  o.h[6] = __float2half(b.z); o.h[7] = __float2half(b.w);
  ((uint4*)d)[i] = o.u;
}

// ---------------------------------------------------------------------------
// W_hh -> int8, 16-k-chunk layout: WQ4[slice][ch(16)][row(1024)] uint4
// q = clamp(round(w * 2048), -127, 127); row = gate*256 + j
// ---------------------------------------------------------------------------
__global__ __launch_bounds__(256) void conv_wq4(const float* __restrict__ src,
                                                uint4* __restrict__ dst) {
  const int s = blockIdx.y;
  const int idx = blockIdx.x * 256 + threadIdx.x;   // 0..16383
  const int row = idx & 1023;
  const int ch = idx >> 10;
  const float* sp = src + (size_t)s * 262144 + (size_t)row * 256 + ch * 16;
  unsigned int u[4];
#pragma unroll
  for (int g4 = 0; g4 < 4; ++g4) {
    const float4 v = *(const float4*)(sp + 4 * g4);
    const float vv[4] = {v.x, v.y, v.z, v.w};
    unsigned int packed = 0;
#pragma unroll
    for (int i = 0; i < 4; i++) {
      int q = (int)rintf(vv[i] * 2048.f);
      q = max(-127, min(127, q));
      packed |= ((unsigned int)(q & 0xFF)) << (8 * i);
    }
    u[g4] = packed;
  }
  dst[(size_t)s * 16384 + (size_t)ch * 1024 + row] = make_uint4(u[0], u[1], u[2], u[3]);
}

// ---------------------------------------------------------------------------
// MFMA f16 GEMM: xg[dir][m][n] = sum_k A[m][k]*W[dir][n][k] + bias[dir][n]
// ---------------------------------------------------------------------------
template <int DK, bool XL>
__global__ __launch_bounds__(256) void xg_gemm_h(const __half* __restrict__ A,
                                                 const __half* __restrict__ W,
                                                 const float* __restrict__ bias,
                                                 __half* __restrict__ xg) {
  const int dir = blockIdx.x >> 4;
  const int n0 = (blockIdx.x & 15) * 64;
  const int m0 = blockIdx.y * 64;
  const __half* Wd = W + (size_t)dir * (1024 * DK);
  const float* bd = bias + dir * 1024;
  __half* out = xg + (size_t)dir * (16384ull * 1024);

  __shared__ __align__(16) __half As[64][40];
  __shared__ __align__(16) __half Bs[64][40];

  const int tid = threadIdx.x;
  const int wave = tid >> 6, lane = tid & 63;
  const int fr = lane & 15, kg = lane >> 4;

  v4f acc[4];
#pragma unroll
  for (int i = 0; i < 4; i++) acc[i] = (v4f)(0.f);

  const int lr = tid >> 2;          // load row 0..63
  const int lc = (tid & 3) * 8;     // k offset
  size_t abase;
  if (XL) {
    const int m = m0 + lr, t = m >> 5, bb = m & 31;
    abase = ((size_t)(bb * 512 + t)) * DK + lc;
  } else {
    abase = (size_t)(m0 + lr) * DK + lc;
  }
  const size_t bbase = (size_t)(n0 + lr) * DK + lc;

  for (int k0 = 0; k0 < DK; k0 += 32) {
    *(uint4*)&As[lr][lc] = *(const uint4*)(A + abase + k0);
    *(uint4*)&Bs[lr][lc] = *(const uint4*)(Wd + bbase + k0);
    __syncthreads();
    const v8hf af = *(const v8hf*)&As[wave * 16 + fr][kg * 8];
#pragma unroll
    for (int nb = 0; nb < 4; ++nb) {
      const v8hf bf = *(const v8hf*)&Bs[nb * 16 + fr][kg * 8];
      acc[nb] = __builtin_amdgcn_mfma_f32_16x16x32_f16(af, bf, acc[nb], 0, 0, 0);
    }
    __syncthreads();
  }

#pragma unroll
  for (int nb = 0; nb < 4; ++nb) {
    const int n = n0 + nb * 16 + fr;
    const float bv = bd[n];
#pragma unroll
    for (int r = 0; r < 4; ++r) {
      const int m = m0 + wave * 16 + kg * 4 + r;
      out[(size_t)m * 1024 + n] = __float2half(acc[nb][r] + bv);
    }
  }
}

// ---------------------------------------------------------------------------
// LSTM layer v9 (int8, register-pinned W): one WG per (dir,batch) chain;
// block 512 = 8 waves. tid = gh*256 + j; thread owns gate rows (2gh, 2gh+1).
// W (16 chunks of 16 k): chunks 0..3 LDS (64 KB, b128 reads), chunks 4..15
// PINNED in VGPRs via opaque asm (24 uint4 = 96 VGPR) -> zero W traffic.
// h int8 double-buffered as uint4[16]; gh1 pre-transforms (tanh g, sig o).
// ---------------------------------------------------------------------------
__global__ __launch_bounds__(512, 1) void lstm_layer9(const uint4* __restrict__ WQ4,
                                                      const __half* __restrict__ xg,
                                                      const int* __restrict__ lens,
                                                      __half* __restrict__ out) {
  const int w = blockIdx.x, dir = w >> 5, b = w & 31;
  const int tid = threadIdx.x, gh = tid >> 8, j = tid & 255;
  const int row0 = (2 * gh) * 256 + j;
  const int row1 = row0 + 256;

  __shared__ __align__(16) uint4 Wc[4 * 1024];   // 64 KB: chunks 0..3
  __shared__ __align__(16) uint4 hq4[2][16];     // 512 B
  __shared__ __align__(16) float aex[2][256];    // 2 KB

  const uint4* __restrict__ Wt = WQ4 + (size_t)dir * 16384;

  // LDS chunks 0..3 (4096 uint4, 8 per thread)
#pragma unroll
  for (int i = 0; i < 8; ++i)
    Wc[i * 512 + tid] = Wt[i * 512 + tid];

  // register-pinned chunks 4..15
  uint4 s0[12], s1[12];
#pragma unroll
  for (int ch = 0; ch < 12; ++ch) {
    s0[ch] = Wt[(size_t)(4 + ch) * 1024 + row0];
    s1[ch] = Wt[(size_t)(4 + ch) * 1024 + row1];
  }
#pragma unroll
  for (int ch = 0; ch < 12; ++ch) {
    asm volatile("" : "+v"(s0[ch].x), "+v"(s0[ch].y), "+v"(s0[ch].z), "+v"(s0[ch].w));
    asm volatile("" : "+v"(s1[ch].x), "+v"(s1[ch].y), "+v"(s1[ch].z), "+v"(s1[ch].w));
  }

  if (tid < 64) ((unsigned int*)&hq4[0][0])[tid] = 0u;
  const int mylen = lens[b];
  float c = 0.f;

  const __half* xgb = xg + (size_t)dir * (512ull * 32 * 1024) + (size_t)b * 1024 + j;
  int tt = dir ? (mylen - 1) : 0;
  float p0, p1;
  {
    const __half* xr = xgb + (size_t)tt * (32 * 1024);
    p0 = __half2float(xr[(2 * gh) * 256]);
    p1 = __half2float(xr[(2 * gh + 1) * 256]);
  }
  __syncthreads();

#pragma unroll 1
  for (int t = 0; t < 512; ++t) {
    const int tcur = tt;
    const uint4* hp = &hq4[t & 1][0];
    int A0 = 0, B0 = 0, A1 = 0, B1 = 0;

    // LDS-resident chunks 0..3
#pragma unroll
    for (int ch = 0; ch < 4; ++ch) {
      const uint4 hv = hp[ch];
      dotc(Wc[ch * 1024 + row0], hv, A0, B0);
      dotc(Wc[ch * 1024 + row1], hv, A1, B1);
    }
    // register-pinned chunks 4..15
#pragma unroll
    for (int ch = 0; ch < 12; ++ch) {
      const uint4 hv = hp[4 + ch];
      dotc(s0[ch], hv, A0, B0);
      dotc(s1[ch], hv, A1, B1);
    }

    const float a0 = (float)(A0 + B0) * 3.844734e-6f + p0;  // 1/(2048*127)
    const float a1 = (float)(A1 + B1) * 3.844734e-6f + p1;

    if (gh == 1) {                       // gates g, o -> pre-transform
      aex[0][j] = tanhf_(a0);
      aex[1][j] = sigmoidf_(a1);
    }
    __syncthreads();
    if (gh == 0) {                       // gates i, f + state update
      const float ig = sigmoidf_(a0);
      const float fg = sigmoidf_(a1);
      c = fg * c + ig * aex[0][j];
      const float hnew = aex[1][j] * tanhf_(c);
      out[((size_t)tcur * 32 + b) * 512 + dir * 256 + j] =
          __float2half((tcur < mylen) ? hnew : 0.f);
      const int q = (int)rintf(hnew * 127.f);
      ((signed char*)&hq4[(t + 1) & 1][0])[j] = (signed char)q;
    }
    if (t < 511) {
      const int tn = t + 1;
      tt = dir ? ((tn < mylen) ? (mylen - 1 - tn) : tn) : tn;
      const __half* xr = xgb + (size_t)tt * (32 * 1024);
      p0 = __half2float(xr[(2 * gh) * 256]);
      p1 = __half2float(xr[(2 * gh + 1) * 256]);
    }
    __syncthreads();
  }
}

// ---------------------------------------------------------------------------
// emit GEMM + fused row-softmax:
// S[m][e] = outA[m][:] . fcwh[e][:] + fcb[e]; emit[(b*512+t)*64+e] = softmax_e
// grid 256 (m0 = blk*64), block 256 (4 waves); mfma 16x16x32 f16.
// ---------------------------------------------------------------------------
__global__ __launch_bounds__(256) void emit_gemm(const __half* __restrict__ outA,
                                                 const __half* __restrict__ fcwh,
                                                 const float* __restrict__ fcb,
                                                 float* __restrict__ emit) {
  const int m0 = blockIdx.x * 64;
  __shared__ __align__(16) __half As[64][40];
  __shared__ __align__(16) __half Bs[64][40];

  const int tid = threadIdx.x;
  const int wave = tid >> 6, lane = tid & 63;
  const int fr = lane & 15, kg = lane >> 4;

  v4f acc[4];
#pragma unroll
  for (int i = 0; i < 4; i++) acc[i] = (v4f)(0.f);

  const int lr = tid >> 2;
  const int lc = (tid & 3) * 8;
  const size_t abase = (size_t)(m0 + lr) * 512 + lc;
  const size_t bbase = (size_t)lr * 512 + lc;

  for (int k0 = 0; k0 < 512; k0 += 32) {
    *(uint4*)&As[lr][lc] = *(const uint4*)(outA + abase + k0);
    *(uint4*)&Bs[lr][lc] = *(const uint4*)(fcwh + bbase + k0);
    __syncthreads();
    const v8hf af = *(const v8hf*)&As[wave * 16 + fr][kg * 8];
#pragma unroll
    for (int nb = 0; nb < 4; ++nb) {
      const v8hf bf = *(const v8hf*)&Bs[nb * 16 + fr][kg * 8];
      acc[nb] = __builtin_amdgcn_mfma_f32_16x16x32_f16(af, bf, acc[nb], 0, 0, 0);
    }
    __syncthreads();
  }

  float bv[4];
#pragma unroll
  for (int nb = 0; nb < 4; ++nb) bv[nb] = fcb[nb * 16 + fr];

#pragma unroll
  for (int r = 0; r < 4; ++r) {
    float v0 = acc[0][r] + bv[0], v1 = acc[1][r] + bv[1];
    float v2 = acc[2][r] + bv[2], v3 = acc[3][r] + bv[3];
    float mx = fmaxf(fmaxf(v0, v1), fmaxf(v2, v3));
#pragma unroll
    for (int off = 8; off; off >>= 1) mx = fmaxf(mx, __shfl_xor(mx, off));
    const float e0 = __expf(v0 - mx), e1 = __expf(v1 - mx);
    const float e2 = __expf(v2 - mx), e3 = __expf(v3 - mx);
    float sm = (e0 + e1) + (e2 + e3);
#pragma unroll
    for (int off = 8; off; off >>= 1) sm += __shfl_xor(sm, off);
    const float rinv = 1.f / sm;
    const int mrow = m0 + wave * 16 + kg * 4 + r;
    const int bb = mrow & 31, ttt = mrow >> 5;
    float* ep = emit + ((size_t)bb * 512 + ttt) * 64;
    ep[0 * 16 + fr] = e0 * rinv;
    ep[1 * 16 + fr] = e1 * rinv;
    ep[2 * 16 + fr] = e2 * rinv;
    ep[3 * 16 + fr] = e3 * rinv;
  }
}

__global__ __launch_bounds__(256) void score_kernel(const float* __restrict__ emit,
                                                    const float* __restrict__ trans,
                                                    const int* __restrict__ tags,
                                                    const int* __restrict__ lens,
                                                    float* __restrict__ total) {
  const int b = blockIdx.x;
  const int len = lens[b];
  float part = 0.f;
  for (int t = threadIdx.x; t < len; t += 256) {
    const int tg = tags[b * Ll + t];
    float v = emit[((size_t)b * Ll + t) * Ee + tg];
    if (t >= 1) v += trans[tags[b * Ll + t - 1] * Ee + tg];
    part += v;
  }
  for (int off = 32; off; off >>= 1) part += __shfl_xor(part, off);
  __shared__ float wsum[4];
  if ((threadIdx.x & 63) == 0) wsum[threadIdx.x >> 6] = part;
  __syncthreads();
  if (threadIdx.x == 0) total[b] = wsum[0] + wsum[1] + wsum[2] + wsum[3];
}

// ---------------------------------------------------------------------------
// CRF prep: cm[j] = max_k trans[k][j]; E[j][k] = exp(trans[k][j] - cm[j])
// ---------------------------------------------------------------------------
__global__ __launch_bounds__(64) void crf_prep(const float* __restrict__ trans,
                                               float* __restrict__ E,
                                               float* __restrict__ cm) {
  const int j = threadIdx.x;
  float m = -1e30f;
  for (int k = 0; k < 64; k++) m = fmaxf(m, trans[k * 64 + j]);
  cm[j] = m;
  for (int k = 0; k < 64; k++) E[j * 64 + k] = __expf(trans[k * 64 + j] - m);
}

// ---------------------------------------------------------------------------
// CRF scan v2 (factorized): d_new[j] = log(sum_k e_k * E[j][k]) + maxd + cm[j]
// ---------------------------------------------------------------------------
__global__ __launch_bounds__(64) void crf_scan2(const float* __restrict__ emit,
                                                const float* __restrict__ E,
                                                const float* __restrict__ cm,
                                                const int* __restrict__ lens,
                                                float* __restrict__ dout) {
  const int b = blockIdx.x, j = threadIdx.x;
  __shared__ float el[2][64];
  float Er[64];
#pragma unroll
  for (int kc = 0; kc < 16; ++kc) {
    const float4 v = *(const float4*)(E + j * 64 + 4 * kc);
    Er[4 * kc + 0] = v.x; Er[4 * kc + 1] = v.y;
    Er[4 * kc + 2] = v.z; Er[4 * kc + 3] = v.w;
  }
  const float cmj = cm[j];
  const int len = lens[b];
  const float* eb = emit + (size_t)b * 512 * 64 + j;
  float d = eb[0];
  float enext = (len > 1) ? eb[64] : 0.f;

  for (int t = 1; t < len; ++t) {
    float m = d;
#pragma unroll
    for (int off = 32; off; off >>= 1) m = fmaxf(m, __shfl_xor(m, off));
    const float ej = __expf(d - m);
    el[t & 1][j] = ej;
    const float emt = enext;
    if (t + 1 < len) enext = eb[(size_t)(t + 1) * 64];
    __syncthreads();
    float s0 = 0.f, s1 = 0.f, s2 = 0.f, s3 = 0.f;
    const float4* e4 = (const float4*)&el[t & 1][0];
#pragma unroll
    for (int kc = 0; kc < 16; ++kc) {
      const float4 ev = e4[kc];
      s0 = fmaf(ev.x, Er[4 * kc + 0], s0);
      s1 = fmaf(ev.y, Er[4 * kc + 1], s1);
      s2 = fmaf(ev.z, Er[4 * kc + 2], s2);
      s3 = fmaf(ev.w, Er[4 * kc + 3], s3);
    }
    d = __logf((s0 + s1) + (s2 + s3)) + m + cmj + emt;
    __syncthreads();
  }
  dout[b * 64 + j] = d;
}

__global__ __launch_bounds__(64) void final_kernel(const float* __restrict__ dbuf,
                                                   const float* __restrict__ total,
                                                   const int* __restrict__ lens,
                                                   float* __restrict__ out) {
  const int j = threadIdx.x;
  float lsum = 0.f;
  for (int b = 0; b < 32; b++) {
    const float d = dbuf[b * 64 + j];
    float m = d;
    for (int off = 32; off; off >>= 1) m = fmaxf(m, __shfl_xor(m, off));
    const float e = __expf(d - m);
    float s = e;
    for (int off = 32; off; off >>= 1) s += __shfl_xor(s, off);
    const float Z = __logf(s) + m;
    if (j == 0) lsum += -(total[b] - Z) / (float)lens[b];
  }
  if (j == 0) out[0] = lsum / 32.f;
}

// ---------------------------------------------------------------------------
extern "C" void kernel_launch(void* const* d_in, const int* in_sizes, int n_in,
                              void* d_out, int out_size, void* d_ws, size_t ws_size,
                              hipStream_t stream) {
  const float* x = (const float*)d_in[0];
  const int* lens = (const int*)d_in[1];
  const int* tags = (const int*)d_in[2];
  const float* w_ih_l0 = (const float*)d_in[4];
  const float* w_hh_l0 = (const float*)d_in[5];
  const float* b_l0 = (const float*)d_in[6];
  const float* w_ih_l12 = (const float*)d_in[7];
  const float* w_hh_l12 = (const float*)d_in[8];
  const float* b_l12 = (const float*)d_in[9];
  const float* fc_w = (const float*)d_in[10];
  const float* fc_b = (const float*)d_in[11];
  const float* trans = (const float*)d_in[12];

  char* ws = (char*)d_ws;
  __half* xg = (__half*)ws;                          // 64 MiB
  __half* xh = (__half*)(ws + 67108864);             // 32 MiB
  __half* outA = (__half*)(ws + 100663296);          // 16 MiB
  __half* outB = (__half*)(ws + 117440512);          // 16 MiB
  uint4* WQ4 = (uint4*)(ws + 134217728);             // 1.5 MiB (whh int8, chunk layout)
  __half* WIH0 = (__half*)(ws + 137363456);          // 4 MiB
  __half* WIH12 = (__half*)(ws + 141557760);         // 4 MiB
  float* Ebuf = (float*)(ws + 145752064);            // 16 KiB
  float* cmbuf = (float*)(ws + 145768448);           // 256 B
  __half* fcwh = (__half*)(ws + 145768960);          // 64 KiB
  // CRF buffers alias the (dead-by-then) xg region
  float* emit = (float*)ws;                          // 4 MiB
  float* total = (float*)(ws + 4194304);
  float* dbuf = total + 32;

  // one-time conversions + CRF prep
  cvt_h<<<8192, 256, 0, stream>>>(x, xh, 2097152);
  cvt_h<<<1024, 256, 0, stream>>>(w_ih_l0, WIH0, 262144);
  cvt_h<<<1024, 256, 0, stream>>>(w_ih_l12, WIH12, 262144);
  cvt_h<<<16, 256, 0, stream>>>(fc_w, fcwh, 4096);
  conv_wq4<<<dim3(64, 2), 256, 0, stream>>>(w_hh_l0, WQ4);
  conv_wq4<<<dim3(64, 4), 256, 0, stream>>>(w_hh_l12, WQ4 + 2 * 16384);
  crf_prep<<<1, 64, 0, stream>>>(trans, Ebuf, cmbuf);

  const dim3 ggrid(32, 256);

  // layer 0
  xg_gemm_h<1024, true><<<ggrid, 256, 0, stream>>>(xh, WIH0, b_l0, xg);
  lstm_layer9<<<64, 512, 0, stream>>>(WQ4, xg, lens, outA);

  // layer 1
  xg_gemm_h<512, false><<<ggrid, 256, 0, stream>>>(outA, WIH12, b_l12, xg);
  lstm_layer9<<<64, 512, 0, stream>>>(WQ4 + 2 * 16384, xg, lens, outB);

  // layer 2
  xg_gemm_h<512, false><<<ggrid, 256, 0, stream>>>(outB, WIH12 + 2 * 1024 * 512,
                                                   b_l12 + 2 * 1024, xg);
  lstm_layer9<<<64, 512, 0, stream>>>(WQ4 + 4 * 16384, xg, lens, outA);

  // CRF
  emit_gemm<<<256, 256, 0, stream>>>(outA, fcwh, fc_b, emit);
  score_kernel<<<Bb, 256, 0, stream>>>(emit, trans, tags, lens, total);
  crf_scan2<<<Bb, 64, 0, stream>>>(emit, Ebuf, cmbuf, lens, dbuf);
  final_kernel<<<1, 64, 0, stream>>>(dbuf, total, lens, (float*)d_out);
}